// Round 8
// baseline (696.848 us; speedup 1.0000x reference)
//
#include <hip/hip_runtime.h>
#include <hip/hip_bf16.h>

#define N_ATOMS 15000
#define N_EDGES 300000
#define FDIM 128
#define NRBF 20
#define CUTOFF 5.0f
#define PI_F 3.14159265358979323846f
#define MT 16            // atoms per MFMA block (MLP kernels)
#define NBLK 938         // ceil(15000/16)

typedef __hip_bfloat16 bf16;
using bf16x8 = __attribute__((ext_vector_type(8))) short;  // 8 bf16 (4 VGPRs)
using f32x4  = __attribute__((ext_vector_type(4))) float;  // 4 f32 acc

#define MFMA(a, b, c) __builtin_amdgcn_mfma_f32_16x16x32_bf16(a, b, c, 0, 0, 0)

__device__ __forceinline__ float b2f(bf16 v) { return __bfloat162float(v); }
__device__ __forceinline__ float siluf(float x) { return x / (1.0f + __expf(-x)); }
__device__ __forceinline__ float lo_bf(unsigned u) { return __uint_as_float(u << 16); }
__device__ __forceinline__ float hi_bf(unsigned u) { return __uint_as_float(u & 0xffff0000u); }
// fp8 e4m3 via gfx950 HW converts (encode+decode use same HW interp -> self-consistent)
__device__ __forceinline__ unsigned char f32_fp8(float x) {
    int p = __builtin_amdgcn_cvt_pk_fp8_f32(x, x, 0, false);
    return (unsigned char)(p & 0xff);
}
__device__ __forceinline__ float fp8_f32(unsigned int b) {
    return __builtin_amdgcn_cvt_f32_fp8(b, 0);
}

// ---- converted-parameter offsets (f32 elements) -----------------------------
__device__ __constant__ int c_off[15] = {
    0, 900000, 912800, 935840, 936992, 986144, 986528, 1133984,
    1135136, 1233440, 1234208, 1332512, 1332896, 1480352, 1481504};
#define P_TOTAL 1481504
#define P_RIJ 0
#define P_EMB 900000
#define P_FW  912800
#define P_FB  935840
#define P_IW1 936992
#define P_IB1 986144
#define P_IW2 986528
#define P_IB2 1133984
#define P_MW  1135136
#define P_MB  1233440
#define P_AW1 1234208
#define P_AB1 1332512
#define P_AW2 1332896
#define P_AB2 1480352

// packed-weight (bf16) layout: per layer 180224 elems:
//   iW1 @0 (128x128), iW2 @16384 (128x384), mW @65536 (128x256),
//   aW1 @98304 (256x128), aW2 @131072 (128x384)
#define WPACK_L 180224
// packed filter weights: per layer 32x384 (K padded to 32, fb at k=20)
#define FWP_L 12288

// ---------------------------------------------------------------------------
__global__ void detect_dtype(const void* __restrict__ r_ij, int* __restrict__ flag) {
    __shared__ int cnt;
    if (threadIdx.x == 0) cnt = 0;
    __syncthreads();
    const bf16* p = (const bf16*)r_ij;
    float v = fabsf(b2f(p[threadIdx.x]));
    int ok = (v > 0.0009765625f && v < 16.0f) ? 1 : 0;
    atomicAdd(&cnt, ok);
    __syncthreads();
    if (threadIdx.x == 0) flag[0] = (cnt > 204) ? 1 : 0;
}

struct CvtArgs { const void* src[14]; };

__global__ void convert_all(CvtArgs args, float* __restrict__ dst,
                            const int* __restrict__ flag) {
    int i = blockIdx.x * blockDim.x + threadIdx.x;
    if (i >= P_TOTAL) return;
    bool isbf = flag[0] != 0;
    int s = 0;
    while (i >= c_off[s + 1]) s++;
    int k = i - c_off[s];
    dst[i] = isbf ? b2f(((const bf16*)args.src[s])[k])
                  : ((const float*)args.src[s])[k];
}

// ---------------------------------------------------------------------------
// Pack 5 weight matrices x 3 layers into MFMA-B fragment order.
// ---------------------------------------------------------------------------
__global__ void pack_w(const float* __restrict__ fp, bf16* __restrict__ wbf) {
    int i = blockIdx.x * blockDim.x + threadIdx.x;
    if (i >= 3 * WPACK_L) return;
    int l = i / WPACK_L;
    int r = i - l * WPACK_L;
    int m, off;
    if (r < 16384)       { m = 0; off = r; }
    else if (r < 65536)  { m = 1; off = r - 16384; }
    else if (r < 98304)  { m = 2; off = r - 65536; }
    else if (r < 131072) { m = 3; off = r - 98304; }
    else                 { m = 4; off = r - 131072; }
    const int pkN[5] = {128, 384, 256, 128, 384};
    const int pkD[5] = {0, 16384, 65536, 98304, 131072};
    int N = pkN[m];
    int k = off / N;
    int n = off - k * N;
    int srcb;
    switch (m) {
        case 0: srcb = P_IW1 + l * 16384; break;
        case 1: srcb = P_IW2 + l * 49152; break;
        case 2: srcb = P_MW  + l * 32768; break;
        case 3: srcb = P_AW1 + l * 32768; break;
        default: srcb = P_AW2 + l * 49152; break;
    }
    float v = fp[srcb + off];
    int dst = l * WPACK_L + pkD[m] +
              (((k >> 5) * 4 + ((k >> 3) & 3)) * N + n) * 8 + (k & 7);
    wbf[dst] = __float2bfloat16(v);
}

// Pack filter weights: B[k][n], k=0..19 -> fW[k][l*384+n], k=20 -> fb, 21..31 -> 0
__global__ void pack_fw(const float* __restrict__ fp, bf16* __restrict__ dst) {
    int i = blockIdx.x * blockDim.x + threadIdx.x;
    if (i >= 3 * FWP_L) return;
    int l = i / FWP_L;
    int r = i - l * FWP_L;
    int k = r / 384;
    int n = r - k * 384;
    float v = 0.0f;
    if (k < 20)       v = fp[P_FW + k * 1152 + l * 384 + n];
    else if (k == 20) v = fp[P_FB + l * 384 + n];
    int di = l * FWP_L + (((k >> 3) * 384) + n) * 8 + (k & 7);
    dst[di] = __float2bfloat16(v);
}

// ---------------------------------------------------------------------------
__global__ void init_q(const int* __restrict__ zn, const float* __restrict__ emb,
                       float* __restrict__ q) {
    int idx = blockIdx.x * blockDim.x + threadIdx.x;
    if (idx >= N_ATOMS * FDIM) return;
    int a = idx >> 7;
    int f = idx & 127;
    q[idx] = emb[zn[a] * FDIM + f];
}

// ---------------------------------------------------------------------------
// Edge sort by idx_i
// ---------------------------------------------------------------------------
__global__ void hist_kernel(const int* __restrict__ idx_i, int* __restrict__ counts) {
    int e = blockIdx.x * blockDim.x + threadIdx.x;
    if (e < N_EDGES) atomicAdd(&counts[idx_i[e]], 1);
}

__global__ void scan_kernel(const int* __restrict__ counts, int* __restrict__ start) {
    __shared__ int partial[256];
    int t = threadIdx.x;
    const int chunk = (N_ATOMS + 255) / 256;
    int base = t * chunk;
    int sum = 0;
    for (int k = 0; k < chunk; k++)
        if (base + k < N_ATOMS) sum += counts[base + k];
    partial[t] = sum;
    __syncthreads();
    for (int off = 1; off < 256; off <<= 1) {
        int v = (t >= off) ? partial[t - off] : 0;
        __syncthreads();
        partial[t] += v;
        __syncthreads();
    }
    int run = (t == 0) ? 0 : partial[t - 1];
    for (int k = 0; k < chunk; k++) {
        if (base + k < N_ATOMS) {
            start[base + k] = run;
            run += counts[base + k];
        }
    }
    if (t == 255) start[N_ATOMS] = run;
}

__global__ void scatter_kernel(const float* __restrict__ r3,
                               const int* __restrict__ idx_i,
                               const int* __restrict__ idx_j,
                               const int* __restrict__ start,
                               int* __restrict__ cursor,
                               int* __restrict__ sorted_j,
                               bf16* __restrict__ edata) {
    int e = blockIdx.x * blockDim.x + threadIdx.x;
    if (e >= N_EDGES) return;
    float xx = r3[e * 3 + 0];
    float yy = r3[e * 3 + 1];
    float zz = r3[e * 3 + 2];
    float d = sqrtf(xx * xx + yy * yy + zz * zz);
    float inv = 1.0f / d;
    float fc = (d < CUTOFF) ? 0.5f * (cosf(d * PI_F / CUTOFF) + 1.0f) : 0.0f;
    const float width = CUTOFF / (float)(NRBF - 1);
    const float coeff = -0.5f / (width * width);
    int i = idx_i[e];
    int pos = start[i] + atomicAdd(&cursor[i], 1);
    sorted_j[pos] = idx_j[e];
    bf16* out = edata + (size_t)pos * 24;
#pragma unroll
    for (int r = 0; r < NRBF; r++) {
        float t = d - width * (float)r;
        out[r] = __float2bfloat16(__expf(coeff * t * t) * fc);
    }
    out[20] = __float2bfloat16(fc);
    out[21] = __float2bfloat16(xx * inv);
    out[22] = __float2bfloat16(yy * inv);
    out[23] = __float2bfloat16(zz * inv);
}

// ---------------------------------------------------------------------------
// Inter MLP via MFMA: 16 atoms/block, 4 waves.
// ---------------------------------------------------------------------------
__global__ __launch_bounds__(256) void inter_mfma(
    const float* __restrict__ q, const bf16* __restrict__ wl,
    const float* __restrict__ b1, const float* __restrict__ b2,
    bf16* __restrict__ xbf) {
    const int t = threadIdx.x;
    const int wave = t >> 6, lane = t & 63, quad = lane >> 4, l15 = lane & 15;
    const int a0 = blockIdx.x * MT;
    __shared__ __align__(16) bf16 sA[MT * 136];
    __shared__ __align__(16) bf16 sH[MT * 136];
    for (int idx = t; idx < MT * 128; idx += 256) {
        int a = idx >> 7, f = idx & 127;
        int ga = a0 + a; if (ga > N_ATOMS - 1) ga = N_ATOMS - 1;
        sA[a * 136 + f] = __float2bfloat16(q[(size_t)ga * 128 + f]);
    }
    __syncthreads();
    const f32x4 fz = {0.0f, 0.0f, 0.0f, 0.0f};
    f32x4 acc0[2] = {fz, fz};
    const bf16* B1 = wl;
#pragma unroll
    for (int kt = 0; kt < 4; kt++) {
        bf16x8 af = *(const bf16x8*)(sA + l15 * 136 + kt * 32 + quad * 8);
#pragma unroll
        for (int n = 0; n < 2; n++) {
            int c0 = (wave * 2 + n) * 16;
            bf16x8 bfr = *(const bf16x8*)(B1 + (((kt * 4 + quad) * 128) + c0 + l15) * 8);
            acc0[n] = MFMA(af, bfr, acc0[n]);
        }
    }
#pragma unroll
    for (int n = 0; n < 2; n++) {
        int col = (wave * 2 + n) * 16 + l15;
        float bb = b1[col];
#pragma unroll
        for (int r = 0; r < 4; r++) {
            int row = quad * 4 + r;
            sH[row * 136 + col] = __float2bfloat16(siluf(acc0[n][r] + bb));
        }
    }
    __syncthreads();
    f32x4 acc2[6] = {fz, fz, fz, fz, fz, fz};
    const bf16* B2 = wl + 16384;
#pragma unroll
    for (int kt = 0; kt < 4; kt++) {
        bf16x8 af = *(const bf16x8*)(sH + l15 * 136 + kt * 32 + quad * 8);
#pragma unroll
        for (int n = 0; n < 6; n++) {
            int c0 = (wave * 6 + n) * 16;
            bf16x8 bfr = *(const bf16x8*)(B2 + (((kt * 4 + quad) * 384) + c0 + l15) * 8);
            acc2[n] = MFMA(af, bfr, acc2[n]);
        }
    }
#pragma unroll
    for (int n = 0; n < 6; n++) {
        int col = (wave * 6 + n) * 16 + l15;
        float bb = b2[col];
#pragma unroll
        for (int r = 0; r < 4; r++) {
            int row = quad * 4 + r;
            int ga = a0 + row;
            if (ga < N_ATOMS)
                xbf[(size_t)ga * 384 + col] = __float2bfloat16(acc2[n][r] + bb);
        }
    }
}

// ---------------------------------------------------------------------------
// Gather with MFMA filters: ONE atom per block, 256 threads.
// mu gathered as fp8-e4m3 (use_mu=0 in layer 0: mu==0, stream skipped).
// ---------------------------------------------------------------------------
__global__ __launch_bounds__(256) void gather_mfma(
    const int* __restrict__ start, const int* __restrict__ sorted_j,
    const bf16* __restrict__ edata,
    const bf16* __restrict__ xbf, const unsigned char* __restrict__ mufp8,
    const bf16* __restrict__ fWp, int use_mu,
    float* __restrict__ q, float* __restrict__ mu) {
    const int t = threadIdx.x;
    const int wave = t >> 6, lane = t & 63, quad = lane >> 4, l15 = lane & 15;
    const int a = blockIdx.x;
    __shared__ __align__(16) bf16 sPHI[32 * 40];    // 2560 B
    __shared__ __align__(16) bf16 sFILT[32 * 392];  // 25088 B
    __shared__ float sDIR[32][4];                   // 512 B
    __shared__ int sJ[32];                          // 128 B
    __shared__ float sRED[512];                     // 2048 B

    const int s0 = start[a];
    const int s4 = start[a + 1];
    const int nE = s4 - s0;
    const int nChunks = (nE + 31) >> 5;
    const int g = t >> 7, f = t & 127;

    // preload B fragments (6 ntiles per wave, K=32 in one k-tile)
    bf16x8 bfrag[6];
#pragma unroll
    for (int n6 = 0; n6 < 6; n6++) {
        int n = wave * 96 + n6 * 16 + l15;
        bfrag[n6] = *(const bf16x8*)(fWp + ((size_t)(quad * 384 + n)) * 8);
    }
    const f32x4 fz = {0.0f, 0.0f, 0.0f, 0.0f};

    float c0 = 0.0f, c1 = 0.0f, c2 = 0.0f, c3 = 0.0f;

    for (int ch = 0; ch < nChunks; ch++) {
        int ebase = s0 + ch * 32;
        // ---- stage up to 32 edges ----
        if (t < 128) {
            int e = t >> 2, part = t & 3;
            int pos = ebase + e;
            bool valid = pos < s4;
            if (part == 3) {
                *(uint4*)(sPHI + e * 40 + 24) = make_uint4(0, 0, 0, 0);
                sJ[e] = valid ? sorted_j[pos] : 0;
            } else {
                uint4 u = valid ? ((const uint4*)(edata + (size_t)pos * 24))[part]
                                : make_uint4(0, 0, 0, 0);
                if (part == 2) {
                    sDIR[e][0] = hi_bf(u.z);
                    sDIR[e][1] = lo_bf(u.w);
                    sDIR[e][2] = hi_bf(u.w);
                    u.z &= 0x0000ffffu;  // keep fc (elem20), zero elem21
                    u.w = 0u;
                }
                *(uint4*)(sPHI + e * 40 + part * 8) = u;
            }
        }
        __syncthreads();
        // ---- MFMA: filters[32][384] ----
#pragma unroll
        for (int mt = 0; mt < 2; mt++) {
            bf16x8 af = *(const bf16x8*)(sPHI + (mt * 16 + l15) * 40 + quad * 8);
#pragma unroll
            for (int n6 = 0; n6 < 6; n6++) {
                f32x4 c = MFMA(af, bfrag[n6], fz);
                int col = wave * 96 + n6 * 16 + l15;
#pragma unroll
                for (int r = 0; r < 4; r++)
                    sFILT[(mt * 16 + quad * 4 + r) * 392 + col] = __float2bfloat16(c[r]);
            }
        }
        __syncthreads();
        // ---- apply: halves alternate edges, pure register accumulation ----
        for (int e = g; e < 32; e += 2) {
            int pos = ebase + e;
            if (pos >= s4) break;
            float f0 = b2f(sFILT[e * 392 + f]);
            float f1 = b2f(sFILT[e * 392 + 128 + f]);
            float f2 = b2f(sFILT[e * 392 + 256 + f]);
            size_t jb = (size_t)sJ[e] * 384;
            float xj0 = b2f(xbf[jb + f]);
            float xj1 = b2f(xbf[jb + 128 + f]);
            float xj2 = b2f(xbf[jb + 256 + f]);
            float d0 = sDIR[e][0], d1 = sDIR[e][1], d2 = sDIR[e][2];
            float dmuR = f1 * xj1;
            c0 += f0 * xj0;
            if (use_mu) {
                float dmm = f2 * xj2;
                float m0 = fp8_f32(mufp8[jb + f]);
                float m1 = fp8_f32(mufp8[jb + 128 + f]);
                float m2 = fp8_f32(mufp8[jb + 256 + f]);
                c1 += dmuR * d0 + dmm * m0;
                c2 += dmuR * d1 + dmm * m1;
                c3 += dmuR * d2 + dmm * m2;
            } else {
                c1 += dmuR * d0;
                c2 += dmuR * d1;
                c3 += dmuR * d2;
            }
        }
        __syncthreads();  // protect sPHI/sFILT before next chunk's staging
    }
    // ---- cross-half reduction + global update ----
    if (g == 0) {
        sRED[f] = c0;
        sRED[128 + f] = c1;
        sRED[256 + f] = c2;
        sRED[384 + f] = c3;
    }
    __syncthreads();
    if (g == 1) {
        q[(size_t)a * 128 + f] += c0 + sRED[f];
        size_t mb = (size_t)a * 384;
        mu[mb + f]       += c1 + sRED[128 + f];
        mu[mb + 128 + f] += c2 + sRED[256 + f];
        mu[mb + 256 + f] += c3 + sRED[384 + f];
    }
}

// ---------------------------------------------------------------------------
// Fused per-atom update via MFMA: 16 atoms/block, 4 waves.
// Writes fp8 mu mirror for next layer's gather.
// ---------------------------------------------------------------------------
__global__ __launch_bounds__(256) void update_mfma(
    float* __restrict__ q, float* __restrict__ mu, unsigned char* __restrict__ mufp8,
    const bf16* __restrict__ wl,
    const float* __restrict__ mixb, const float* __restrict__ ib1,
    const float* __restrict__ ib2) {
    const int t = threadIdx.x;
    const int wave = t >> 6, lane = t & 63, quad = lane >> 4, l15 = lane & 15;
    const int a0 = blockIdx.x * MT;
    __shared__ __align__(16) char lds[47360];
    bf16* sMU  = (bf16*)lds;
    bf16* sCTX = (bf16*)lds;
    bf16* sH2  = (bf16*)(lds + 8448);
    bf16* sV   = (bf16*)(lds + 13056);
    bf16* sX2  = (bf16*)(lds + 13056);
    bf16* sW   = (bf16*)(lds + 26112);
    float* sSD = (float*)(lds + 39168);

    for (int idx = t; idx < 48 * 128; idx += 256) {
        int row = idx >> 7, f = idx & 127;
        int a = row / 3, s = row - a * 3;
        int ga = a0 + a; if (ga > N_ATOMS - 1) ga = N_ATOMS - 1;
        sMU[row * 136 + f] = __float2bfloat16(mu[(size_t)ga * 384 + s * 128 + f]);
    }
    __syncthreads();
    const f32x4 fz = {0.0f, 0.0f, 0.0f, 0.0f};
    const bf16* BM = wl + 65536;
    bf16x8 bfr[4][4];
#pragma unroll
    for (int kt = 0; kt < 4; kt++)
#pragma unroll
        for (int n = 0; n < 4; n++) {
            int c0 = (wave * 4 + n) * 16;
            bfr[n][kt] = *(const bf16x8*)(BM + (((kt * 4 + quad) * 256) + c0 + l15) * 8);
        }
    f32x4 accm[3][4];
#pragma unroll
    for (int mt = 0; mt < 3; mt++)
#pragma unroll
        for (int n = 0; n < 4; n++) accm[mt][n] = fz;
#pragma unroll
    for (int mt = 0; mt < 3; mt++) {
#pragma unroll
        for (int kt = 0; kt < 4; kt++) {
            bf16x8 af = *(const bf16x8*)(sMU + (mt * 16 + l15) * 136 + kt * 32 + quad * 8);
#pragma unroll
            for (int n = 0; n < 4; n++)
                accm[mt][n] = MFMA(af, bfr[n][kt], accm[mt][n]);
        }
    }
    __syncthreads();
#pragma unroll
    for (int mt = 0; mt < 3; mt++)
#pragma unroll
        for (int n = 0; n < 4; n++) {
            int col = wave * 64 + n * 16 + l15;
            float bb = mixb[col];
#pragma unroll
            for (int r = 0; r < 4; r++) {
                int row = mt * 16 + quad * 4 + r;
                float v = accm[mt][n][r] + bb;
                if (col < 128) sV[row * 136 + col] = __float2bfloat16(v);
                else           sW[row * 136 + col - 128] = __float2bfloat16(v);
            }
        }
    __syncthreads();
    for (int idx = t; idx < MT * 128; idx += 256) {
        int a = idx >> 7, f = idx & 127;
        float v0 = b2f(sV[(a * 3 + 0) * 136 + f]);
        float v1 = b2f(sV[(a * 3 + 1) * 136 + f]);
        float v2 = b2f(sV[(a * 3 + 2) * 136 + f]);
        float w0 = b2f(sW[(a * 3 + 0) * 136 + f]);
        float w1 = b2f(sW[(a * 3 + 1) * 136 + f]);
        float w2 = b2f(sW[(a * 3 + 2) * 136 + f]);
        sSD[a * 128 + f] = v0 * w0 + v1 * w1 + v2 * w2;
        float vn = sqrtf(v0 * v0 + v1 * v1 + v2 * v2);
        int ga = a0 + a; if (ga > N_ATOMS - 1) ga = N_ATOMS - 1;
        sCTX[a * 264 + f] = __float2bfloat16(q[(size_t)ga * 128 + f]);
        sCTX[a * 264 + 128 + f] = __float2bfloat16(vn);
    }
    __syncthreads();
    const bf16* BA1 = wl + 98304;
    f32x4 acc1[2] = {fz, fz};
#pragma unroll
    for (int kt = 0; kt < 8; kt++) {
        bf16x8 af = *(const bf16x8*)(sCTX + l15 * 264 + kt * 32 + quad * 8);
#pragma unroll
        for (int n = 0; n < 2; n++) {
            int c0 = (wave * 2 + n) * 16;
            bf16x8 bb = *(const bf16x8*)(BA1 + (((kt * 4 + quad) * 128) + c0 + l15) * 8);
            acc1[n] = MFMA(af, bb, acc1[n]);
        }
    }
#pragma unroll
    for (int n = 0; n < 2; n++) {
        int col = (wave * 2 + n) * 16 + l15;
        float bb = ib1[col];
#pragma unroll
        for (int r = 0; r < 4; r++) {
            int row = quad * 4 + r;
            sH2[row * 136 + col] = __float2bfloat16(siluf(acc1[n][r] + bb));
        }
    }
    __syncthreads();
    const bf16* BA2 = wl + 131072;
    f32x4 acc3[6] = {fz, fz, fz, fz, fz, fz};
#pragma unroll
    for (int kt = 0; kt < 4; kt++) {
        bf16x8 af = *(const bf16x8*)(sH2 + l15 * 136 + kt * 32 + quad * 8);
#pragma unroll
        for (int n = 0; n < 6; n++) {
            int c0 = (wave * 6 + n) * 16;
            bf16x8 bb = *(const bf16x8*)(BA2 + (((kt * 4 + quad) * 384) + c0 + l15) * 8);
            acc3[n] = MFMA(af, bb, acc3[n]);
        }
    }
#pragma unroll
    for (int n = 0; n < 6; n++) {
        int col = (wave * 6 + n) * 16 + l15;
        float bb = ib2[col];
#pragma unroll
        for (int r = 0; r < 4; r++) {
            int row = quad * 4 + r;
            sX2[row * 392 + col] = __float2bfloat16(acc3[n][r] + bb);
        }
    }
    __syncthreads();
    for (int idx = t; idx < MT * 128; idx += 256) {
        int a = idx >> 7, f = idx & 127;
        int ga = a0 + a;
        if (ga >= N_ATOMS) continue;
        float x0 = b2f(sX2[a * 392 + f]);
        float x1 = b2f(sX2[a * 392 + 128 + f]);
        float x2 = b2f(sX2[a * 392 + 256 + f]);
        float sd = sSD[a * 128 + f];
        q[(size_t)ga * 128 + f] += x0 + x2 * sd;
#pragma unroll
        for (int s = 0; s < 3; s++) {
            float w = b2f(sW[(a * 3 + s) * 136 + f]);
            size_t off = (size_t)ga * 384 + s * 128 + f;
            float m = mu[off] + x1 * w;
            mu[off] = m;
            mufp8[off] = f32_fp8(m);
        }
    }
}

// ---------------------------------------------------------------------------
__global__ void writeout(const float* __restrict__ q, const float* __restrict__ mu,
                         void* __restrict__ out, const int* __restrict__ flag) {
    int idx = blockIdx.x * blockDim.x + threadIdx.x;
    const int nq = N_ATOMS * FDIM;
    const int ntot = N_ATOMS * 4 * FDIM;
    if (idx >= ntot) return;
    float v = (idx < nq) ? q[idx] : mu[idx - nq];
    if (flag[0] != 0) ((bf16*)out)[idx] = __float2bfloat16(v);
    else              ((float*)out)[idx] = v;
}

extern "C" void kernel_launch(void* const* d_in, const int* in_sizes, int n_in,
                              void* d_out, int out_size, void* d_ws, size_t ws_size,
                              hipStream_t stream) {
    const int* zn    = (const int*)d_in[14];
    const int* idx_i = (const int*)d_in[15];
    const int* idx_j = (const int*)d_in[16];

    char* base = (char*)d_ws;
    int*   flag     = (int*)base;
    float* fp       = (float*)(base + 256);
    float* q        = (float*)(base + 256 + 5926016);
    float* mu       = (float*)(base + 256 + 5926016 + 7680000);
    bf16*  xbf      = (bf16*)(base + 36646272);
    unsigned char* mufp8 = (unsigned char*)(base + 48166272);  // 5.76 MB (was bf16 11.5)
    int*   counts   = (int*)(base + 59686272);
    int*   cursor   = (int*)(base + 59746304);
    int*   startarr = (int*)(base + 59806336);
    int*   sorted_j = (int*)(base + 59866368);
    bf16*  edata    = (bf16*)(base + 61066368);   // ends ~75.5 MB
    // packed weights alias dead r_ij-f32 region (written after scatter)
    bf16*  wbf      = (bf16*)fp;
    bf16*  fWp      = wbf + 3 * WPACK_L;          // +73.7 KB, still inside r_ij region

    detect_dtype<<<1, 256, 0, stream>>>(d_in[0], flag);

    CvtArgs ca;
    for (int t = 0; t < 14; t++) ca.src[t] = d_in[t];
    convert_all<<<(P_TOTAL + 255) / 256, 256, 0, stream>>>(ca, fp, flag);

    const float* r3  = fp + P_RIJ;
    const float* emb = fp + P_EMB;

    hipMemsetAsync(counts, 0, 2 * 60032, stream);
    hist_kernel<<<(N_EDGES + 255) / 256, 256, 0, stream>>>(idx_i, counts);
    scan_kernel<<<1, 256, 0, stream>>>(counts, startarr);
    scatter_kernel<<<(N_EDGES + 255) / 256, 256, 0, stream>>>(
        r3, idx_i, idx_j, startarr, cursor, sorted_j, edata);

    // r3 now dead -> pack weights over it
    pack_w<<<(3 * WPACK_L + 255) / 256, 256, 0, stream>>>(fp, wbf);
    pack_fw<<<(3 * FWP_L + 255) / 256, 256, 0, stream>>>(fp, fWp);

    hipMemsetAsync(mu, 0, (size_t)N_ATOMS * 3 * FDIM * sizeof(float), stream);
    init_q<<<(N_ATOMS * FDIM + 255) / 256, 256, 0, stream>>>(zn, emb, q);

    for (int l = 0; l < 3; l++) {
        const bf16* wl = wbf + (size_t)l * WPACK_L;
        inter_mfma<<<NBLK, 256, 0, stream>>>(
            q, wl, fp + P_IB1 + l * 128, fp + P_IB2 + l * 384, xbf);
        gather_mfma<<<N_ATOMS, 256, 0, stream>>>(
            startarr, sorted_j, edata, xbf, mufp8, fWp + (size_t)l * FWP_L,
            (l > 0) ? 1 : 0, q, mu);
        update_mfma<<<NBLK, 256, 0, stream>>>(
            q, mu, mufp8, wl,
            fp + P_MB + l * 256, fp + P_AB1 + l * 128, fp + P_AB2 + l * 384);
    }

    int ntot = N_ATOMS * 4 * FDIM;
    writeout<<<(ntot + 255) / 256, 256, 0, stream>>>(q, mu, d_out, flag);
}

// Round 9
// 626.538 us; speedup vs baseline: 1.1122x; 1.1122x over previous
//
#include <hip/hip_runtime.h>
#include <hip/hip_bf16.h>

#define N_ATOMS 15000
#define N_EDGES 300000
#define FDIM 128
#define NRBF 20
#define CUTOFF 5.0f
#define PI_F 3.14159265358979323846f
#define MT 16            // atoms per MFMA block (MLP kernels)
#define NBLK 938         // ceil(15000/16)

typedef __hip_bfloat16 bf16;
using bf16x8 = __attribute__((ext_vector_type(8))) short;  // 8 bf16 (4 VGPRs)
using f32x4  = __attribute__((ext_vector_type(4))) float;  // 4 f32 acc

#define MFMA(a, b, c) __builtin_amdgcn_mfma_f32_16x16x32_bf16(a, b, c, 0, 0, 0)

__device__ __forceinline__ float b2f(bf16 v) { return __bfloat162float(v); }
__device__ __forceinline__ float siluf(float x) { return x / (1.0f + __expf(-x)); }
__device__ __forceinline__ float lo_bf(unsigned u) { return __uint_as_float(u << 16); }
__device__ __forceinline__ float hi_bf(unsigned u) { return __uint_as_float(u & 0xffff0000u); }
// fp8 e4m3 via gfx950 HW converts (encode+decode same HW interp -> self-consistent)
__device__ __forceinline__ unsigned char f32_fp8(float x) {
    int p = __builtin_amdgcn_cvt_pk_fp8_f32(x, x, 0, false);
    return (unsigned char)(p & 0xff);
}
__device__ __forceinline__ float fp8_f32(unsigned int b) {
    return __builtin_amdgcn_cvt_f32_fp8(b, 0);
}

// ---- converted-parameter offsets (f32 elements) -----------------------------
__device__ __constant__ int c_off[15] = {
    0, 900000, 912800, 935840, 936992, 986144, 986528, 1133984,
    1135136, 1233440, 1234208, 1332512, 1332896, 1480352, 1481504};
#define P_TOTAL 1481504
#define P_RIJ 0
#define P_EMB 900000
#define P_FW  912800
#define P_FB  935840
#define P_IW1 936992
#define P_IB1 986144
#define P_IW2 986528
#define P_IB2 1133984
#define P_MW  1135136
#define P_MB  1233440
#define P_AW1 1234208
#define P_AB1 1332512
#define P_AW2 1332896
#define P_AB2 1480352

// packed-weight (bf16) layout per layer: 180224 elems
#define WPACK_L 180224
// packed filter weights: per layer 32x384 (K padded to 32, fb at k=20)
#define FWP_L 12288

// ---------------------------------------------------------------------------
__global__ void detect_dtype(const void* __restrict__ r_ij, int* __restrict__ flag) {
    __shared__ int cnt;
    if (threadIdx.x == 0) cnt = 0;
    __syncthreads();
    const bf16* p = (const bf16*)r_ij;
    float v = fabsf(b2f(p[threadIdx.x]));
    int ok = (v > 0.0009765625f && v < 16.0f) ? 1 : 0;
    atomicAdd(&cnt, ok);
    __syncthreads();
    if (threadIdx.x == 0) flag[0] = (cnt > 204) ? 1 : 0;
}

struct CvtArgs { const void* src[14]; };

__global__ void convert_all(CvtArgs args, float* __restrict__ dst,
                            const int* __restrict__ flag) {
    int i = blockIdx.x * blockDim.x + threadIdx.x;
    if (i >= P_TOTAL) return;
    bool isbf = flag[0] != 0;
    int s = 0;
    while (i >= c_off[s + 1]) s++;
    int k = i - c_off[s];
    dst[i] = isbf ? b2f(((const bf16*)args.src[s])[k])
                  : ((const float*)args.src[s])[k];
}

// ---------------------------------------------------------------------------
__global__ void pack_w(const float* __restrict__ fp, bf16* __restrict__ wbf) {
    int i = blockIdx.x * blockDim.x + threadIdx.x;
    if (i >= 3 * WPACK_L) return;
    int l = i / WPACK_L;
    int r = i - l * WPACK_L;
    int m, off;
    if (r < 16384)       { m = 0; off = r; }
    else if (r < 65536)  { m = 1; off = r - 16384; }
    else if (r < 98304)  { m = 2; off = r - 65536; }
    else if (r < 131072) { m = 3; off = r - 98304; }
    else                 { m = 4; off = r - 131072; }
    const int pkN[5] = {128, 384, 256, 128, 384};
    const int pkD[5] = {0, 16384, 65536, 98304, 131072};
    int N = pkN[m];
    int k = off / N;
    int n = off - k * N;
    int srcb;
    switch (m) {
        case 0: srcb = P_IW1 + l * 16384; break;
        case 1: srcb = P_IW2 + l * 49152; break;
        case 2: srcb = P_MW  + l * 32768; break;
        case 3: srcb = P_AW1 + l * 32768; break;
        default: srcb = P_AW2 + l * 49152; break;
    }
    float v = fp[srcb + off];
    int dst = l * WPACK_L + pkD[m] +
              (((k >> 5) * 4 + ((k >> 3) & 3)) * N + n) * 8 + (k & 7);
    wbf[dst] = __float2bfloat16(v);
}

__global__ void pack_fw(const float* __restrict__ fp, bf16* __restrict__ dst) {
    int i = blockIdx.x * blockDim.x + threadIdx.x;
    if (i >= 3 * FWP_L) return;
    int l = i / FWP_L;
    int r = i - l * FWP_L;
    int k = r / 384;
    int n = r - k * 384;
    float v = 0.0f;
    if (k < 20)       v = fp[P_FW + k * 1152 + l * 384 + n];
    else if (k == 20) v = fp[P_FB + l * 384 + n];
    int di = l * FWP_L + (((k >> 3) * 384) + n) * 8 + (k & 7);
    dst[di] = __float2bfloat16(v);
}

// ---------------------------------------------------------------------------
__global__ void init_q(const int* __restrict__ zn, const float* __restrict__ emb,
                       float* __restrict__ q) {
    int idx = blockIdx.x * blockDim.x + threadIdx.x;
    if (idx >= N_ATOMS * FDIM) return;
    int a = idx >> 7;
    int f = idx & 127;
    q[idx] = emb[zn[a] * FDIM + f];
}

// ---------------------------------------------------------------------------
__global__ void hist_kernel(const int* __restrict__ idx_i, int* __restrict__ counts) {
    int e = blockIdx.x * blockDim.x + threadIdx.x;
    if (e < N_EDGES) atomicAdd(&counts[idx_i[e]], 1);
}

__global__ void scan_kernel(const int* __restrict__ counts, int* __restrict__ start) {
    __shared__ int partial[256];
    int t = threadIdx.x;
    const int chunk = (N_ATOMS + 255) / 256;
    int base = t * chunk;
    int sum = 0;
    for (int k = 0; k < chunk; k++)
        if (base + k < N_ATOMS) sum += counts[base + k];
    partial[t] = sum;
    __syncthreads();
    for (int off = 1; off < 256; off <<= 1) {
        int v = (t >= off) ? partial[t - off] : 0;
        __syncthreads();
        partial[t] += v;
        __syncthreads();
    }
    int run = (t == 0) ? 0 : partial[t - 1];
    for (int k = 0; k < chunk; k++) {
        if (base + k < N_ATOMS) {
            start[base + k] = run;
            run += counts[base + k];
        }
    }
    if (t == 255) start[N_ATOMS] = run;
}

__global__ void scatter_kernel(const float* __restrict__ r3,
                               const int* __restrict__ idx_i,
                               const int* __restrict__ idx_j,
                               const int* __restrict__ start,
                               int* __restrict__ cursor,
                               int* __restrict__ sorted_j,
                               bf16* __restrict__ edata) {
    int e = blockIdx.x * blockDim.x + threadIdx.x;
    if (e >= N_EDGES) return;
    float xx = r3[e * 3 + 0];
    float yy = r3[e * 3 + 1];
    float zz = r3[e * 3 + 2];
    float d = sqrtf(xx * xx + yy * yy + zz * zz);
    float inv = 1.0f / d;
    float fc = (d < CUTOFF) ? 0.5f * (cosf(d * PI_F / CUTOFF) + 1.0f) : 0.0f;
    const float width = CUTOFF / (float)(NRBF - 1);
    const float coeff = -0.5f / (width * width);
    int i = idx_i[e];
    int pos = start[i] + atomicAdd(&cursor[i], 1);
    sorted_j[pos] = idx_j[e];
    bf16* out = edata + (size_t)pos * 24;
#pragma unroll
    for (int r = 0; r < NRBF; r++) {
        float t = d - width * (float)r;
        out[r] = __float2bfloat16(__expf(coeff * t * t) * fc);
    }
    out[20] = __float2bfloat16(fc);
    out[21] = __float2bfloat16(xx * inv);
    out[22] = __float2bfloat16(yy * inv);
    out[23] = __float2bfloat16(zz * inv);
}

// ---------------------------------------------------------------------------
// Inter MLP via MFMA: 16 atoms/block, 4 waves.
// ---------------------------------------------------------------------------
__global__ __launch_bounds__(256) void inter_mfma(
    const float* __restrict__ q, const bf16* __restrict__ wl,
    const float* __restrict__ b1, const float* __restrict__ b2,
    bf16* __restrict__ xbf) {
    const int t = threadIdx.x;
    const int wave = t >> 6, lane = t & 63, quad = lane >> 4, l15 = lane & 15;
    const int a0 = blockIdx.x * MT;
    __shared__ __align__(16) bf16 sA[MT * 136];
    __shared__ __align__(16) bf16 sH[MT * 136];
    for (int idx = t; idx < MT * 128; idx += 256) {
        int a = idx >> 7, f = idx & 127;
        int ga = a0 + a; if (ga > N_ATOMS - 1) ga = N_ATOMS - 1;
        sA[a * 136 + f] = __float2bfloat16(q[(size_t)ga * 128 + f]);
    }
    __syncthreads();
    const f32x4 fz = {0.0f, 0.0f, 0.0f, 0.0f};
    f32x4 acc0[2] = {fz, fz};
    const bf16* B1 = wl;
#pragma unroll
    for (int kt = 0; kt < 4; kt++) {
        bf16x8 af = *(const bf16x8*)(sA + l15 * 136 + kt * 32 + quad * 8);
#pragma unroll
        for (int n = 0; n < 2; n++) {
            int c0 = (wave * 2 + n) * 16;
            bf16x8 bfr = *(const bf16x8*)(B1 + (((kt * 4 + quad) * 128) + c0 + l15) * 8);
            acc0[n] = MFMA(af, bfr, acc0[n]);
        }
    }
#pragma unroll
    for (int n = 0; n < 2; n++) {
        int col = (wave * 2 + n) * 16 + l15;
        float bb = b1[col];
#pragma unroll
        for (int r = 0; r < 4; r++) {
            int row = quad * 4 + r;
            sH[row * 136 + col] = __float2bfloat16(siluf(acc0[n][r] + bb));
        }
    }
    __syncthreads();
    f32x4 acc2[6] = {fz, fz, fz, fz, fz, fz};
    const bf16* B2 = wl + 16384;
#pragma unroll
    for (int kt = 0; kt < 4; kt++) {
        bf16x8 af = *(const bf16x8*)(sH + l15 * 136 + kt * 32 + quad * 8);
#pragma unroll
        for (int n = 0; n < 6; n++) {
            int c0 = (wave * 6 + n) * 16;
            bf16x8 bfr = *(const bf16x8*)(B2 + (((kt * 4 + quad) * 384) + c0 + l15) * 8);
            acc2[n] = MFMA(af, bfr, acc2[n]);
        }
    }
#pragma unroll
    for (int n = 0; n < 6; n++) {
        int col = (wave * 6 + n) * 16 + l15;
        float bb = b2[col];
#pragma unroll
        for (int r = 0; r < 4; r++) {
            int row = quad * 4 + r;
            int ga = a0 + row;
            if (ga < N_ATOMS)
                xbf[(size_t)ga * 384 + col] = __float2bfloat16(acc2[n][r] + bb);
        }
    }
}

// ---------------------------------------------------------------------------
// Gather kernels: ONE atom per block, 256 threads, branch-free hot loops.
// Two variants: L0 (mu==0, no mu stream) and MU (fp8 mu, unconditional).
// ---------------------------------------------------------------------------
#define GATHER_PROLOGUE                                                        \
    const int t = threadIdx.x;                                                 \
    const int wave = t >> 6, lane = t & 63, quad = lane >> 4, l15 = lane & 15; \
    const int a = blockIdx.x;                                                  \
    __shared__ __align__(16) bf16 sPHI[32 * 40];                               \
    __shared__ __align__(16) bf16 sFILT[32 * 392];                             \
    __shared__ float sDIR[32][4];                                              \
    __shared__ int sJ[32];                                                     \
    __shared__ float sRED[512];                                                \
    const int s0 = start[a];                                                   \
    const int s4 = start[a + 1];                                               \
    const int nE = s4 - s0;                                                    \
    const int nChunks = (nE + 31) >> 5;                                        \
    const int g = t >> 7, f = t & 127;                                         \
    bf16x8 bfrag[6];                                                           \
    _Pragma("unroll")                                                          \
    for (int n6 = 0; n6 < 6; n6++) {                                           \
        int n = wave * 96 + n6 * 16 + l15;                                     \
        bfrag[n6] = *(const bf16x8*)(fWp + ((size_t)(quad * 384 + n)) * 8);    \
    }                                                                          \
    const f32x4 fz = {0.0f, 0.0f, 0.0f, 0.0f};                                 \
    float c0 = 0.0f, c1 = 0.0f, c2 = 0.0f, c3 = 0.0f;

#define GATHER_STAGE_AND_MFMA                                                  \
        int ebase = s0 + ch * 32;                                              \
        if (t < 128) {                                                         \
            int e = t >> 2, part = t & 3;                                      \
            int pos = ebase + e;                                               \
            bool valid = pos < s4;                                             \
            if (part == 3) {                                                   \
                *(uint4*)(sPHI + e * 40 + 24) = make_uint4(0, 0, 0, 0);        \
                sJ[e] = valid ? sorted_j[pos] : 0;                             \
            } else {                                                           \
                uint4 u = valid ? ((const uint4*)(edata + (size_t)pos * 24))[part] \
                                : make_uint4(0, 0, 0, 0);                      \
                if (part == 2) {                                               \
                    sDIR[e][0] = hi_bf(u.z);                                   \
                    sDIR[e][1] = lo_bf(u.w);                                   \
                    sDIR[e][2] = hi_bf(u.w);                                   \
                    u.z &= 0x0000ffffu;                                        \
                    u.w = 0u;                                                  \
                }                                                              \
                *(uint4*)(sPHI + e * 40 + part * 8) = u;                       \
            }                                                                  \
        }                                                                      \
        __syncthreads();                                                       \
        _Pragma("unroll")                                                      \
        for (int mt = 0; mt < 2; mt++) {                                       \
            bf16x8 af = *(const bf16x8*)(sPHI + (mt * 16 + l15) * 40 + quad * 8); \
            _Pragma("unroll")                                                  \
            for (int n6 = 0; n6 < 6; n6++) {                                   \
                f32x4 c = MFMA(af, bfrag[n6], fz);                             \
                int col = wave * 96 + n6 * 16 + l15;                           \
                _Pragma("unroll")                                              \
                for (int r = 0; r < 4; r++)                                    \
                    sFILT[(mt * 16 + quad * 4 + r) * 392 + col] = __float2bfloat16(c[r]); \
            }                                                                  \
        }                                                                      \
        __syncthreads();

#define GATHER_EPILOGUE                                                        \
    if (g == 0) {                                                              \
        sRED[f] = c0;                                                          \
        sRED[128 + f] = c1;                                                    \
        sRED[256 + f] = c2;                                                    \
        sRED[384 + f] = c3;                                                    \
    }                                                                          \
    __syncthreads();                                                           \
    if (g == 1) {                                                              \
        q[(size_t)a * 128 + f] += c0 + sRED[f];                                \
        size_t mb = (size_t)a * 384;                                           \
        mu[mb + f]       += c1 + sRED[128 + f];                                \
        mu[mb + 128 + f] += c2 + sRED[256 + f];                                \
        mu[mb + 256 + f] += c3 + sRED[384 + f];                                \
    }

__global__ __launch_bounds__(256) void gather_l0(
    const int* __restrict__ start, const int* __restrict__ sorted_j,
    const bf16* __restrict__ edata, const bf16* __restrict__ xbf,
    const bf16* __restrict__ fWp,
    float* __restrict__ q, float* __restrict__ mu) {
    GATHER_PROLOGUE
    for (int ch = 0; ch < nChunks; ch++) {
        GATHER_STAGE_AND_MFMA
        for (int e = g; e < 32; e += 2) {
            int pos = ebase + e;
            if (pos >= s4) break;
            float f0 = b2f(sFILT[e * 392 + f]);
            float f1 = b2f(sFILT[e * 392 + 128 + f]);
            size_t jb = (size_t)sJ[e] * 384;
            float xj0 = b2f(xbf[jb + f]);
            float xj1 = b2f(xbf[jb + 128 + f]);
            float d0 = sDIR[e][0], d1 = sDIR[e][1], d2 = sDIR[e][2];
            float dmuR = f1 * xj1;
            c0 += f0 * xj0;
            c1 += dmuR * d0;
            c2 += dmuR * d1;
            c3 += dmuR * d2;
        }
        __syncthreads();
    }
    GATHER_EPILOGUE
}

__global__ __launch_bounds__(256) void gather_mu(
    const int* __restrict__ start, const int* __restrict__ sorted_j,
    const bf16* __restrict__ edata, const bf16* __restrict__ xbf,
    const unsigned char* __restrict__ mufp8, const bf16* __restrict__ fWp,
    float* __restrict__ q, float* __restrict__ mu) {
    GATHER_PROLOGUE
    for (int ch = 0; ch < nChunks; ch++) {
        GATHER_STAGE_AND_MFMA
        for (int e = g; e < 32; e += 2) {
            int pos = ebase + e;
            if (pos >= s4) break;
            float f0 = b2f(sFILT[e * 392 + f]);
            float f1 = b2f(sFILT[e * 392 + 128 + f]);
            float f2 = b2f(sFILT[e * 392 + 256 + f]);
            size_t jb = (size_t)sJ[e] * 384;
            float xj0 = b2f(xbf[jb + f]);
            float xj1 = b2f(xbf[jb + 128 + f]);
            float xj2 = b2f(xbf[jb + 256 + f]);
            float m0 = fp8_f32(mufp8[jb + f]);
            float m1 = fp8_f32(mufp8[jb + 128 + f]);
            float m2 = fp8_f32(mufp8[jb + 256 + f]);
            float d0 = sDIR[e][0], d1 = sDIR[e][1], d2 = sDIR[e][2];
            float dmuR = f1 * xj1, dmm = f2 * xj2;
            c0 += f0 * xj0;
            c1 += dmuR * d0 + dmm * m0;
            c2 += dmuR * d1 + dmm * m1;
            c3 += dmuR * d2 + dmm * m2;
        }
        __syncthreads();
    }
    GATHER_EPILOGUE
}

// ---------------------------------------------------------------------------
// Fused per-atom update via MFMA: 16 atoms/block, 4 waves. Writes fp8 mirror.
// ---------------------------------------------------------------------------
__global__ __launch_bounds__(256) void update_mfma(
    float* __restrict__ q, float* __restrict__ mu, unsigned char* __restrict__ mufp8,
    const bf16* __restrict__ wl,
    const float* __restrict__ mixb, const float* __restrict__ ib1,
    const float* __restrict__ ib2) {
    const int t = threadIdx.x;
    const int wave = t >> 6, lane = t & 63, quad = lane >> 4, l15 = lane & 15;
    const int a0 = blockIdx.x * MT;
    __shared__ __align__(16) char lds[47360];
    bf16* sMU  = (bf16*)lds;
    bf16* sCTX = (bf16*)lds;
    bf16* sH2  = (bf16*)(lds + 8448);
    bf16* sV   = (bf16*)(lds + 13056);
    bf16* sX2  = (bf16*)(lds + 13056);
    bf16* sW   = (bf16*)(lds + 26112);
    float* sSD = (float*)(lds + 39168);

    for (int idx = t; idx < 48 * 128; idx += 256) {
        int row = idx >> 7, f = idx & 127;
        int a = row / 3, s = row - a * 3;
        int ga = a0 + a; if (ga > N_ATOMS - 1) ga = N_ATOMS - 1;
        sMU[row * 136 + f] = __float2bfloat16(mu[(size_t)ga * 384 + s * 128 + f]);
    }
    __syncthreads();
    const f32x4 fz = {0.0f, 0.0f, 0.0f, 0.0f};
    const bf16* BM = wl + 65536;
    bf16x8 bfr[4][4];
#pragma unroll
    for (int kt = 0; kt < 4; kt++)
#pragma unroll
        for (int n = 0; n < 4; n++) {
            int c0 = (wave * 4 + n) * 16;
            bfr[n][kt] = *(const bf16x8*)(BM + (((kt * 4 + quad) * 256) + c0 + l15) * 8);
        }
    f32x4 accm[3][4];
#pragma unroll
    for (int mt = 0; mt < 3; mt++)
#pragma unroll
        for (int n = 0; n < 4; n++) accm[mt][n] = fz;
#pragma unroll
    for (int mt = 0; mt < 3; mt++) {
#pragma unroll
        for (int kt = 0; kt < 4; kt++) {
            bf16x8 af = *(const bf16x8*)(sMU + (mt * 16 + l15) * 136 + kt * 32 + quad * 8);
#pragma unroll
            for (int n = 0; n < 4; n++)
                accm[mt][n] = MFMA(af, bfr[n][kt], accm[mt][n]);
        }
    }
    __syncthreads();
#pragma unroll
    for (int mt = 0; mt < 3; mt++)
#pragma unroll
        for (int n = 0; n < 4; n++) {
            int col = wave * 64 + n * 16 + l15;
            float bb = mixb[col];
#pragma unroll
            for (int r = 0; r < 4; r++) {
                int row = mt * 16 + quad * 4 + r;
                float v = accm[mt][n][r] + bb;
                if (col < 128) sV[row * 136 + col] = __float2bfloat16(v);
                else           sW[row * 136 + col - 128] = __float2bfloat16(v);
            }
        }
    __syncthreads();
    for (int idx = t; idx < MT * 128; idx += 256) {
        int a = idx >> 7, f = idx & 127;
        float v0 = b2f(sV[(a * 3 + 0) * 136 + f]);
        float v1 = b2f(sV[(a * 3 + 1) * 136 + f]);
        float v2 = b2f(sV[(a * 3 + 2) * 136 + f]);
        float w0 = b2f(sW[(a * 3 + 0) * 136 + f]);
        float w1 = b2f(sW[(a * 3 + 1) * 136 + f]);
        float w2 = b2f(sW[(a * 3 + 2) * 136 + f]);
        sSD[a * 128 + f] = v0 * w0 + v1 * w1 + v2 * w2;
        float vn = sqrtf(v0 * v0 + v1 * v1 + v2 * v2);
        int ga = a0 + a; if (ga > N_ATOMS - 1) ga = N_ATOMS - 1;
        sCTX[a * 264 + f] = __float2bfloat16(q[(size_t)ga * 128 + f]);
        sCTX[a * 264 + 128 + f] = __float2bfloat16(vn);
    }
    __syncthreads();
    const bf16* BA1 = wl + 98304;
    f32x4 acc1[2] = {fz, fz};
#pragma unroll
    for (int kt = 0; kt < 8; kt++) {
        bf16x8 af = *(const bf16x8*)(sCTX + l15 * 264 + kt * 32 + quad * 8);
#pragma unroll
        for (int n = 0; n < 2; n++) {
            int c0 = (wave * 2 + n) * 16;
            bf16x8 bb = *(const bf16x8*)(BA1 + (((kt * 4 + quad) * 128) + c0 + l15) * 8);
            acc1[n] = MFMA(af, bb, acc1[n]);
        }
    }
#pragma unroll
    for (int n = 0; n < 2; n++) {
        int col = (wave * 2 + n) * 16 + l15;
        float bb = ib1[col];
#pragma unroll
        for (int r = 0; r < 4; r++) {
            int row = quad * 4 + r;
            sH2[row * 136 + col] = __float2bfloat16(siluf(acc1[n][r] + bb));
        }
    }
    __syncthreads();
    const bf16* BA2 = wl + 131072;
    f32x4 acc3[6] = {fz, fz, fz, fz, fz, fz};
#pragma unroll
    for (int kt = 0; kt < 4; kt++) {
        bf16x8 af = *(const bf16x8*)(sH2 + l15 * 136 + kt * 32 + quad * 8);
#pragma unroll
        for (int n = 0; n < 6; n++) {
            int c0 = (wave * 6 + n) * 16;
            bf16x8 bb = *(const bf16x8*)(BA2 + (((kt * 4 + quad) * 384) + c0 + l15) * 8);
            acc3[n] = MFMA(af, bb, acc3[n]);
        }
    }
#pragma unroll
    for (int n = 0; n < 6; n++) {
        int col = (wave * 6 + n) * 16 + l15;
        float bb = ib2[col];
#pragma unroll
        for (int r = 0; r < 4; r++) {
            int row = quad * 4 + r;
            sX2[row * 392 + col] = __float2bfloat16(acc3[n][r] + bb);
        }
    }
    __syncthreads();
    for (int idx = t; idx < MT * 128; idx += 256) {
        int a = idx >> 7, f = idx & 127;
        int ga = a0 + a;
        if (ga >= N_ATOMS) continue;
        float x0 = b2f(sX2[a * 392 + f]);
        float x1 = b2f(sX2[a * 392 + 128 + f]);
        float x2 = b2f(sX2[a * 392 + 256 + f]);
        float sd = sSD[a * 128 + f];
        q[(size_t)ga * 128 + f] += x0 + x2 * sd;
#pragma unroll
        for (int s = 0; s < 3; s++) {
            float w = b2f(sW[(a * 3 + s) * 136 + f]);
            size_t off = (size_t)ga * 384 + s * 128 + f;
            float m = mu[off] + x1 * w;
            mu[off] = m;
            mufp8[off] = f32_fp8(m);
        }
    }
}

// ---------------------------------------------------------------------------
__global__ void writeout(const float* __restrict__ q, const float* __restrict__ mu,
                         void* __restrict__ out, const int* __restrict__ flag) {
    int idx = blockIdx.x * blockDim.x + threadIdx.x;
    const int nq = N_ATOMS * FDIM;
    const int ntot = N_ATOMS * 4 * FDIM;
    if (idx >= ntot) return;
    float v = (idx < nq) ? q[idx] : mu[idx - nq];
    if (flag[0] != 0) ((bf16*)out)[idx] = __float2bfloat16(v);
    else              ((float*)out)[idx] = v;
}

extern "C" void kernel_launch(void* const* d_in, const int* in_sizes, int n_in,
                              void* d_out, int out_size, void* d_ws, size_t ws_size,
                              hipStream_t stream) {
    const int* zn    = (const int*)d_in[14];
    const int* idx_i = (const int*)d_in[15];
    const int* idx_j = (const int*)d_in[16];

    char* base = (char*)d_ws;
    int*   flag     = (int*)base;
    float* fp       = (float*)(base + 256);
    float* q        = (float*)(base + 256 + 5926016);
    float* mu       = (float*)(base + 256 + 5926016 + 7680000);
    bf16*  xbf      = (bf16*)(base + 36646272);
    unsigned char* mufp8 = (unsigned char*)(base + 48166272);  // 5.76 MB
    int*   counts   = (int*)(base + 59686272);
    int*   cursor   = (int*)(base + 59746304);
    int*   startarr = (int*)(base + 59806336);
    int*   sorted_j = (int*)(base + 59866368);
    bf16*  edata    = (bf16*)(base + 61066368);   // ends ~75.5 MB
    bf16*  wbf      = (bf16*)fp;                  // aliases dead r_ij region
    bf16*  fWp      = wbf + 3 * WPACK_L;

    detect_dtype<<<1, 256, 0, stream>>>(d_in[0], flag);

    CvtArgs ca;
    for (int t = 0; t < 14; t++) ca.src[t] = d_in[t];
    convert_all<<<(P_TOTAL + 255) / 256, 256, 0, stream>>>(ca, fp, flag);

    const float* r3  = fp + P_RIJ;
    const float* emb = fp + P_EMB;

    hipMemsetAsync(counts, 0, 2 * 60032, stream);
    hist_kernel<<<(N_EDGES + 255) / 256, 256, 0, stream>>>(idx_i, counts);
    scan_kernel<<<1, 256, 0, stream>>>(counts, startarr);
    scatter_kernel<<<(N_EDGES + 255) / 256, 256, 0, stream>>>(
        r3, idx_i, idx_j, startarr, cursor, sorted_j, edata);

    pack_w<<<(3 * WPACK_L + 255) / 256, 256, 0, stream>>>(fp, wbf);
    pack_fw<<<(3 * FWP_L + 255) / 256, 256, 0, stream>>>(fp, fWp);

    hipMemsetAsync(mu, 0, (size_t)N_ATOMS * 3 * FDIM * sizeof(float), stream);
    init_q<<<(N_ATOMS * FDIM + 255) / 256, 256, 0, stream>>>(zn, emb, q);

    for (int l = 0; l < 3; l++) {
        const bf16* wl = wbf + (size_t)l * WPACK_L;
        inter_mfma<<<NBLK, 256, 0, stream>>>(
            q, wl, fp + P_IB1 + l * 128, fp + P_IB2 + l * 384, xbf);
        if (l == 0)
            gather_l0<<<N_ATOMS, 256, 0, stream>>>(
                startarr, sorted_j, edata, xbf, fWp, q, mu);
        else
            gather_mu<<<N_ATOMS, 256, 0, stream>>>(
                startarr, sorted_j, edata, xbf, mufp8, fWp + (size_t)l * FWP_L, q, mu);
        update_mfma<<<NBLK, 256, 0, stream>>>(
            q, mu, mufp8, wl,
            fp + P_MB + l * 256, fp + P_AB1 + l * 128, fp + P_AB2 + l * 384);
    }

    int ntot = N_ATOMS * 4 * FDIM;
    writeout<<<(ntot + 255) / 256, 256, 0, stream>>>(q, mu, d_out, flag);
}

// Round 10
// 602.023 us; speedup vs baseline: 1.1575x; 1.0407x over previous
//
#include <hip/hip_runtime.h>
#include <hip/hip_bf16.h>

#define N_ATOMS 15000
#define N_EDGES 300000
#define FDIM 128
#define NRBF 20
#define CUTOFF 5.0f
#define PI_F 3.14159265358979323846f
#define MT 16            // atoms per MFMA block (MLP kernels)
#define NBLK 938         // ceil(15000/16)

typedef __hip_bfloat16 bf16;
using bf16x8 = __attribute__((ext_vector_type(8))) short;  // 8 bf16 (4 VGPRs)
using f32x4  = __attribute__((ext_vector_type(4))) float;  // 4 f32 acc

#define MFMA(a, b, c) __builtin_amdgcn_mfma_f32_16x16x32_bf16(a, b, c, 0, 0, 0)

__device__ __forceinline__ float b2f(bf16 v) { return __bfloat162float(v); }
__device__ __forceinline__ float siluf(float x) { return x / (1.0f + __expf(-x)); }
__device__ __forceinline__ float lo_bf(unsigned u) { return __uint_as_float(u << 16); }
__device__ __forceinline__ float hi_bf(unsigned u) { return __uint_as_float(u & 0xffff0000u); }
// fp8 e4m3 via gfx950 HW converts (encode+decode same HW interp -> self-consistent)
__device__ __forceinline__ unsigned char f32_fp8(float x) {
    int p = __builtin_amdgcn_cvt_pk_fp8_f32(x, x, 0, false);
    return (unsigned char)(p & 0xff);
}
__device__ __forceinline__ float fp8_f32(unsigned int b) {
    return __builtin_amdgcn_cvt_f32_fp8(b, 0);
}

// ---- converted-parameter offsets (f32 elements) -----------------------------
__device__ __constant__ int c_off[15] = {
    0, 900000, 912800, 935840, 936992, 986144, 986528, 1133984,
    1135136, 1233440, 1234208, 1332512, 1332896, 1480352, 1481504};
#define P_TOTAL 1481504
#define P_RIJ 0
#define P_EMB 900000
#define P_FW  912800
#define P_FB  935840
#define P_IW1 936992
#define P_IB1 986144
#define P_IW2 986528
#define P_IB2 1133984
#define P_MW  1135136
#define P_MB  1233440
#define P_AW1 1234208
#define P_AB1 1332512
#define P_AW2 1332896
#define P_AB2 1480352

// packed-weight (bf16) layout per layer: 180224 elems
#define WPACK_L 180224
// packed filter weights: per layer 32x384 (K padded to 32, fb at k=20)
#define FWP_L 12288

// ---------------------------------------------------------------------------
__global__ void detect_dtype(const void* __restrict__ r_ij, int* __restrict__ flag) {
    __shared__ int cnt;
    if (threadIdx.x == 0) cnt = 0;
    __syncthreads();
    const bf16* p = (const bf16*)r_ij;
    float v = fabsf(b2f(p[threadIdx.x]));
    int ok = (v > 0.0009765625f && v < 16.0f) ? 1 : 0;
    atomicAdd(&cnt, ok);
    __syncthreads();
    if (threadIdx.x == 0) flag[0] = (cnt > 204) ? 1 : 0;
}

struct CvtArgs { const void* src[14]; };

__global__ void convert_all(CvtArgs args, float* __restrict__ dst,
                            const int* __restrict__ flag) {
    int i = blockIdx.x * blockDim.x + threadIdx.x;
    if (i >= P_TOTAL) return;
    bool isbf = flag[0] != 0;
    int s = 0;
    while (i >= c_off[s + 1]) s++;
    int k = i - c_off[s];
    dst[i] = isbf ? b2f(((const bf16*)args.src[s])[k])
                  : ((const float*)args.src[s])[k];
}

// ---------------------------------------------------------------------------
// Pack MLP weights (MFMA-B order) + filter weights in one kernel.
// ---------------------------------------------------------------------------
__global__ void pack_all(const float* __restrict__ fp, bf16* __restrict__ wbf,
                         bf16* __restrict__ fWp) {
    int i = blockIdx.x * blockDim.x + threadIdx.x;
    if (i < 3 * WPACK_L) {
        int l = i / WPACK_L;
        int r = i - l * WPACK_L;
        int m, off;
        if (r < 16384)       { m = 0; off = r; }
        else if (r < 65536)  { m = 1; off = r - 16384; }
        else if (r < 98304)  { m = 2; off = r - 65536; }
        else if (r < 131072) { m = 3; off = r - 98304; }
        else                 { m = 4; off = r - 131072; }
        const int pkN[5] = {128, 384, 256, 128, 384};
        const int pkD[5] = {0, 16384, 65536, 98304, 131072};
        int N = pkN[m];
        int k = off / N;
        int n = off - k * N;
        int srcb;
        switch (m) {
            case 0: srcb = P_IW1 + l * 16384; break;
            case 1: srcb = P_IW2 + l * 49152; break;
            case 2: srcb = P_MW  + l * 32768; break;
            case 3: srcb = P_AW1 + l * 32768; break;
            default: srcb = P_AW2 + l * 49152; break;
        }
        float v = fp[srcb + off];
        int dst = l * WPACK_L + pkD[m] +
                  (((k >> 5) * 4 + ((k >> 3) & 3)) * N + n) * 8 + (k & 7);
        wbf[dst] = __float2bfloat16(v);
    } else if (i < 3 * WPACK_L + 3 * FWP_L) {
        int j = i - 3 * WPACK_L;
        int l = j / FWP_L;
        int r = j - l * FWP_L;
        int k = r / 384;
        int n = r - k * 384;
        float v = 0.0f;
        if (k < 20)       v = fp[P_FW + k * 1152 + l * 384 + n];
        else if (k == 20) v = fp[P_FB + l * 384 + n];
        int di = l * FWP_L + (((k >> 3) * 384) + n) * 8 + (k & 7);
        fWp[di] = __float2bfloat16(v);
    }
}

// ---------------------------------------------------------------------------
// init_q + zero mu in one kernel.
// ---------------------------------------------------------------------------
__global__ void init_state(const int* __restrict__ zn, const float* __restrict__ emb,
                           float* __restrict__ q, float* __restrict__ mu) {
    int idx = blockIdx.x * blockDim.x + threadIdx.x;
    const int nq = N_ATOMS * FDIM;
    const int nm = N_ATOMS * 3 * FDIM;
    if (idx < nq) {
        int a = idx >> 7;
        int f = idx & 127;
        q[idx] = emb[zn[a] * FDIM + f];
    } else if (idx < nq + nm) {
        mu[idx - nq] = 0.0f;
    }
}

// ---------------------------------------------------------------------------
__global__ void hist_kernel(const int* __restrict__ idx_i, int* __restrict__ counts) {
    int e = blockIdx.x * blockDim.x + threadIdx.x;
    if (e < N_EDGES) atomicAdd(&counts[idx_i[e]], 1);
}

__global__ void scan_kernel(const int* __restrict__ counts, int* __restrict__ start) {
    __shared__ int partial[256];
    int t = threadIdx.x;
    const int chunk = (N_ATOMS + 255) / 256;
    int base = t * chunk;
    int sum = 0;
    for (int k = 0; k < chunk; k++)
        if (base + k < N_ATOMS) sum += counts[base + k];
    partial[t] = sum;
    __syncthreads();
    for (int off = 1; off < 256; off <<= 1) {
        int v = (t >= off) ? partial[t - off] : 0;
        __syncthreads();
        partial[t] += v;
        __syncthreads();
    }
    int run = (t == 0) ? 0 : partial[t - 1];
    for (int k = 0; k < chunk; k++) {
        if (base + k < N_ATOMS) {
            start[base + k] = run;
            run += counts[base + k];
        }
    }
    if (t == 255) start[N_ATOMS] = run;
}

__global__ void scatter_kernel(const float* __restrict__ r3,
                               const int* __restrict__ idx_i,
                               const int* __restrict__ idx_j,
                               const int* __restrict__ start,
                               int* __restrict__ cursor,
                               int* __restrict__ sorted_j,
                               bf16* __restrict__ edata) {
    int e = blockIdx.x * blockDim.x + threadIdx.x;
    if (e >= N_EDGES) return;
    float xx = r3[e * 3 + 0];
    float yy = r3[e * 3 + 1];
    float zz = r3[e * 3 + 2];
    float d = sqrtf(xx * xx + yy * yy + zz * zz);
    float inv = 1.0f / d;
    float fc = (d < CUTOFF) ? 0.5f * (cosf(d * PI_F / CUTOFF) + 1.0f) : 0.0f;
    const float width = CUTOFF / (float)(NRBF - 1);
    const float coeff = -0.5f / (width * width);
    int i = idx_i[e];
    int pos = start[i] + atomicAdd(&cursor[i], 1);
    sorted_j[pos] = idx_j[e];
    bf16* out = edata + (size_t)pos * 24;
#pragma unroll
    for (int r = 0; r < NRBF; r++) {
        float t = d - width * (float)r;
        out[r] = __float2bfloat16(__expf(coeff * t * t) * fc);
    }
    out[20] = __float2bfloat16(fc);
    out[21] = __float2bfloat16(xx * inv);
    out[22] = __float2bfloat16(yy * inv);
    out[23] = __float2bfloat16(zz * inv);
}

// ---------------------------------------------------------------------------
// Inter MLP via MFMA: 16 atoms/block, 4 waves.
// ---------------------------------------------------------------------------
__global__ __launch_bounds__(256) void inter_mfma(
    const float* __restrict__ q, const bf16* __restrict__ wl,
    const float* __restrict__ b1, const float* __restrict__ b2,
    bf16* __restrict__ xbf) {
    const int t = threadIdx.x;
    const int wave = t >> 6, lane = t & 63, quad = lane >> 4, l15 = lane & 15;
    const int a0 = blockIdx.x * MT;
    __shared__ __align__(16) bf16 sA[MT * 136];
    __shared__ __align__(16) bf16 sH[MT * 136];
    for (int idx = t; idx < MT * 128; idx += 256) {
        int a = idx >> 7, f = idx & 127;
        int ga = a0 + a; if (ga > N_ATOMS - 1) ga = N_ATOMS - 1;
        sA[a * 136 + f] = __float2bfloat16(q[(size_t)ga * 128 + f]);
    }
    __syncthreads();
    const f32x4 fz = {0.0f, 0.0f, 0.0f, 0.0f};
    f32x4 acc0[2] = {fz, fz};
    const bf16* B1 = wl;
#pragma unroll
    for (int kt = 0; kt < 4; kt++) {
        bf16x8 af = *(const bf16x8*)(sA + l15 * 136 + kt * 32 + quad * 8);
#pragma unroll
        for (int n = 0; n < 2; n++) {
            int c0 = (wave * 2 + n) * 16;
            bf16x8 bfr = *(const bf16x8*)(B1 + (((kt * 4 + quad) * 128) + c0 + l15) * 8);
            acc0[n] = MFMA(af, bfr, acc0[n]);
        }
    }
#pragma unroll
    for (int n = 0; n < 2; n++) {
        int col = (wave * 2 + n) * 16 + l15;
        float bb = b1[col];
#pragma unroll
        for (int r = 0; r < 4; r++) {
            int row = quad * 4 + r;
            sH[row * 136 + col] = __float2bfloat16(siluf(acc0[n][r] + bb));
        }
    }
    __syncthreads();
    f32x4 acc2[6] = {fz, fz, fz, fz, fz, fz};
    const bf16* B2 = wl + 16384;
#pragma unroll
    for (int kt = 0; kt < 4; kt++) {
        bf16x8 af = *(const bf16x8*)(sH + l15 * 136 + kt * 32 + quad * 8);
#pragma unroll
        for (int n = 0; n < 6; n++) {
            int c0 = (wave * 6 + n) * 16;
            bf16x8 bfr = *(const bf16x8*)(B2 + (((kt * 4 + quad) * 384) + c0 + l15) * 8);
            acc2[n] = MFMA(af, bfr, acc2[n]);
        }
    }
#pragma unroll
    for (int n = 0; n < 6; n++) {
        int col = (wave * 6 + n) * 16 + l15;
        float bb = b2[col];
#pragma unroll
        for (int r = 0; r < 4; r++) {
            int row = quad * 4 + r;
            int ga = a0 + row;
            if (ga < N_ATOMS)
                xbf[(size_t)ga * 384 + col] = __float2bfloat16(acc2[n][r] + bb);
        }
    }
}

// ---------------------------------------------------------------------------
// Gather kernels: ONE atom per block, 256 threads.
// Apply loop is FIXED-TRIP (no break): invalid edge slots have zero filters
// (phi rows zeroed incl. fc, so bias term is zero too) and sJ=0 -> their
// contributions are exactly 0. This lets the compiler unroll and batch the
// gather loads (memory-level parallelism) instead of serializing one edge's
// latency at a time.
// ---------------------------------------------------------------------------
#define GATHER_PROLOGUE                                                        \
    const int t = threadIdx.x;                                                 \
    const int wave = t >> 6, lane = t & 63, quad = lane >> 4, l15 = lane & 15; \
    const int a = blockIdx.x;                                                  \
    __shared__ __align__(16) bf16 sPHI[32 * 40];                               \
    __shared__ __align__(16) bf16 sFILT[32 * 392];                             \
    __shared__ float sDIR[32][4];                                              \
    __shared__ int sJ[32];                                                     \
    __shared__ float sRED[512];                                                \
    const int s0 = start[a];                                                   \
    const int s4 = start[a + 1];                                               \
    const int nE = s4 - s0;                                                    \
    const int nChunks = (nE + 31) >> 5;                                        \
    const int g = t >> 7, f = t & 127;                                         \
    bf16x8 bfrag[6];                                                           \
    _Pragma("unroll")                                                          \
    for (int n6 = 0; n6 < 6; n6++) {                                           \
        int n = wave * 96 + n6 * 16 + l15;                                     \
        bfrag[n6] = *(const bf16x8*)(fWp + ((size_t)(quad * 384 + n)) * 8);    \
    }                                                                          \
    const f32x4 fz = {0.0f, 0.0f, 0.0f, 0.0f};                                 \
    float c0 = 0.0f, c1 = 0.0f, c2 = 0.0f, c3 = 0.0f;

#define GATHER_STAGE_AND_MFMA                                                  \
        int ebase = s0 + ch * 32;                                              \
        if (t < 128) {                                                         \
            int e = t >> 2, part = t & 3;                                      \
            int pos = ebase + e;                                               \
            bool valid = pos < s4;                                             \
            if (part == 3) {                                                   \
                *(uint4*)(sPHI + e * 40 + 24) = make_uint4(0, 0, 0, 0);        \
                sJ[e] = valid ? sorted_j[pos] : 0;                             \
            } else {                                                           \
                uint4 u = valid ? ((const uint4*)(edata + (size_t)pos * 24))[part] \
                                : make_uint4(0, 0, 0, 0);                      \
                if (part == 2) {                                               \
                    sDIR[e][0] = hi_bf(u.z);                                   \
                    sDIR[e][1] = lo_bf(u.w);                                   \
                    sDIR[e][2] = hi_bf(u.w);                                   \
                    u.z &= 0x0000ffffu;                                        \
                    u.w = 0u;                                                  \
                }                                                              \
                *(uint4*)(sPHI + e * 40 + part * 8) = u;                       \
            }                                                                  \
        }                                                                      \
        __syncthreads();                                                       \
        _Pragma("unroll")                                                      \
        for (int mt = 0; mt < 2; mt++) {                                       \
            bf16x8 af = *(const bf16x8*)(sPHI + (mt * 16 + l15) * 40 + quad * 8); \
            _Pragma("unroll")                                                  \
            for (int n6 = 0; n6 < 6; n6++) {                                   \
                f32x4 c = MFMA(af, bfrag[n6], fz);                             \
                int col = wave * 96 + n6 * 16 + l15;                           \
                _Pragma("unroll")                                              \
                for (int r = 0; r < 4; r++)                                    \
                    sFILT[(mt * 16 + quad * 4 + r) * 392 + col] = __float2bfloat16(c[r]); \
            }                                                                  \
        }                                                                      \
        __syncthreads();

#define GATHER_EPILOGUE                                                        \
    if (g == 0) {                                                              \
        sRED[f] = c0;                                                          \
        sRED[128 + f] = c1;                                                    \
        sRED[256 + f] = c2;                                                    \
        sRED[384 + f] = c3;                                                    \
    }                                                                          \
    __syncthreads();                                                           \
    if (g == 1) {                                                              \
        q[(size_t)a * 128 + f] += c0 + sRED[f];                                \
        size_t mb = (size_t)a * 384;                                           \
        mu[mb + f]       += c1 + sRED[128 + f];                                \
        mu[mb + 128 + f] += c2 + sRED[256 + f];                                \
        mu[mb + 256 + f] += c3 + sRED[384 + f];                                \
    }

__global__ __launch_bounds__(256) void gather_l0(
    const int* __restrict__ start, const int* __restrict__ sorted_j,
    const bf16* __restrict__ edata, const bf16* __restrict__ xbf,
    const bf16* __restrict__ fWp,
    float* __restrict__ q, float* __restrict__ mu) {
    GATHER_PROLOGUE
    for (int ch = 0; ch < nChunks; ch++) {
        GATHER_STAGE_AND_MFMA
#pragma unroll 4
        for (int e = g; e < 32; e += 2) {
            float f0 = b2f(sFILT[e * 392 + f]);
            float f1 = b2f(sFILT[e * 392 + 128 + f]);
            size_t jb = (size_t)sJ[e] * 384;
            float xj0 = b2f(xbf[jb + f]);
            float xj1 = b2f(xbf[jb + 128 + f]);
            float d0 = sDIR[e][0], d1 = sDIR[e][1], d2 = sDIR[e][2];
            float dmuR = f1 * xj1;
            c0 += f0 * xj0;
            c1 += dmuR * d0;
            c2 += dmuR * d1;
            c3 += dmuR * d2;
        }
        __syncthreads();
    }
    GATHER_EPILOGUE
}

__global__ __launch_bounds__(256) void gather_mu(
    const int* __restrict__ start, const int* __restrict__ sorted_j,
    const bf16* __restrict__ edata, const bf16* __restrict__ xbf,
    const unsigned char* __restrict__ mufp8, const bf16* __restrict__ fWp,
    float* __restrict__ q, float* __restrict__ mu) {
    GATHER_PROLOGUE
    for (int ch = 0; ch < nChunks; ch++) {
        GATHER_STAGE_AND_MFMA
#pragma unroll 4
        for (int e = g; e < 32; e += 2) {
            float f0 = b2f(sFILT[e * 392 + f]);
            float f1 = b2f(sFILT[e * 392 + 128 + f]);
            float f2 = b2f(sFILT[e * 392 + 256 + f]);
            size_t jb = (size_t)sJ[e] * 384;
            float xj0 = b2f(xbf[jb + f]);
            float xj1 = b2f(xbf[jb + 128 + f]);
            float xj2 = b2f(xbf[jb + 256 + f]);
            float m0 = fp8_f32(mufp8[jb + f]);
            float m1 = fp8_f32(mufp8[jb + 128 + f]);
            float m2 = fp8_f32(mufp8[jb + 256 + f]);
            float d0 = sDIR[e][0], d1 = sDIR[e][1], d2 = sDIR[e][2];
            float dmuR = f1 * xj1, dmm = f2 * xj2;
            c0 += f0 * xj0;
            c1 += dmuR * d0 + dmm * m0;
            c2 += dmuR * d1 + dmm * m1;
            c3 += dmuR * d2 + dmm * m2;
        }
        __syncthreads();
    }
    GATHER_EPILOGUE
}

// ---------------------------------------------------------------------------
// Fused per-atom update via MFMA: 16 atoms/block, 4 waves. Writes fp8 mirror.
// ---------------------------------------------------------------------------
__global__ __launch_bounds__(256) void update_mfma(
    float* __restrict__ q, float* __restrict__ mu, unsigned char* __restrict__ mufp8,
    const bf16* __restrict__ wl,
    const float* __restrict__ mixb, const float* __restrict__ ib1,
    const float* __restrict__ ib2) {
    const int t = threadIdx.x;
    const int wave = t >> 6, lane = t & 63, quad = lane >> 4, l15 = lane & 15;
    const int a0 = blockIdx.x * MT;
    __shared__ __align__(16) char lds[47360];
    bf16* sMU  = (bf16*)lds;
    bf16* sCTX = (bf16*)lds;
    bf16* sH2  = (bf16*)(lds + 8448);
    bf16* sV   = (bf16*)(lds + 13056);
    bf16* sX2  = (bf16*)(lds + 13056);
    bf16* sW   = (bf16*)(lds + 26112);
    float* sSD = (float*)(lds + 39168);

    for (int idx = t; idx < 48 * 128; idx += 256) {
        int row = idx >> 7, f = idx & 127;
        int a = row / 3, s = row - a * 3;
        int ga = a0 + a; if (ga > N_ATOMS - 1) ga = N_ATOMS - 1;
        sMU[row * 136 + f] = __float2bfloat16(mu[(size_t)ga * 384 + s * 128 + f]);
    }
    __syncthreads();
    const f32x4 fz = {0.0f, 0.0f, 0.0f, 0.0f};
    const bf16* BM = wl + 65536;
    bf16x8 bfr[4][4];
#pragma unroll
    for (int kt = 0; kt < 4; kt++)
#pragma unroll
        for (int n = 0; n < 4; n++) {
            int c0 = (wave * 4 + n) * 16;
            bfr[n][kt] = *(const bf16x8*)(BM + (((kt * 4 + quad) * 256) + c0 + l15) * 8);
        }
    f32x4 accm[3][4];
#pragma unroll
    for (int mt = 0; mt < 3; mt++)
#pragma unroll
        for (int n = 0; n < 4; n++) accm[mt][n] = fz;
#pragma unroll
    for (int mt = 0; mt < 3; mt++) {
#pragma unroll
        for (int kt = 0; kt < 4; kt++) {
            bf16x8 af = *(const bf16x8*)(sMU + (mt * 16 + l15) * 136 + kt * 32 + quad * 8);
#pragma unroll
            for (int n = 0; n < 4; n++)
                accm[mt][n] = MFMA(af, bfr[n][kt], accm[mt][n]);
        }
    }
    __syncthreads();
#pragma unroll
    for (int mt = 0; mt < 3; mt++)
#pragma unroll
        for (int n = 0; n < 4; n++) {
            int col = wave * 64 + n * 16 + l15;
            float bb = mixb[col];
#pragma unroll
            for (int r = 0; r < 4; r++) {
                int row = mt * 16 + quad * 4 + r;
                float v = accm[mt][n][r] + bb;
                if (col < 128) sV[row * 136 + col] = __float2bfloat16(v);
                else           sW[row * 136 + col - 128] = __float2bfloat16(v);
            }
        }
    __syncthreads();
    for (int idx = t; idx < MT * 128; idx += 256) {
        int a = idx >> 7, f = idx & 127;
        float v0 = b2f(sV[(a * 3 + 0) * 136 + f]);
        float v1 = b2f(sV[(a * 3 + 1) * 136 + f]);
        float v2 = b2f(sV[(a * 3 + 2) * 136 + f]);
        float w0 = b2f(sW[(a * 3 + 0) * 136 + f]);
        float w1 = b2f(sW[(a * 3 + 1) * 136 + f]);
        float w2 = b2f(sW[(a * 3 + 2) * 136 + f]);
        sSD[a * 128 + f] = v0 * w0 + v1 * w1 + v2 * w2;
        float vn = sqrtf(v0 * v0 + v1 * v1 + v2 * v2);
        int ga = a0 + a; if (ga > N_ATOMS - 1) ga = N_ATOMS - 1;
        sCTX[a * 264 + f] = __float2bfloat16(q[(size_t)ga * 128 + f]);
        sCTX[a * 264 + 128 + f] = __float2bfloat16(vn);
    }
    __syncthreads();
    const bf16* BA1 = wl + 98304;
    f32x4 acc1[2] = {fz, fz};
#pragma unroll
    for (int kt = 0; kt < 8; kt++) {
        bf16x8 af = *(const bf16x8*)(sCTX + l15 * 264 + kt * 32 + quad * 8);
#pragma unroll
        for (int n = 0; n < 2; n++) {
            int c0 = (wave * 2 + n) * 16;
            bf16x8 bb = *(const bf16x8*)(BA1 + (((kt * 4 + quad) * 128) + c0 + l15) * 8);
            acc1[n] = MFMA(af, bb, acc1[n]);
        }
    }
#pragma unroll
    for (int n = 0; n < 2; n++) {
        int col = (wave * 2 + n) * 16 + l15;
        float bb = ib1[col];
#pragma unroll
        for (int r = 0; r < 4; r++) {
            int row = quad * 4 + r;
            sH2[row * 136 + col] = __float2bfloat16(siluf(acc1[n][r] + bb));
        }
    }
    __syncthreads();
    const bf16* BA2 = wl + 131072;
    f32x4 acc3[6] = {fz, fz, fz, fz, fz, fz};
#pragma unroll
    for (int kt = 0; kt < 4; kt++) {
        bf16x8 af = *(const bf16x8*)(sH2 + l15 * 136 + kt * 32 + quad * 8);
#pragma unroll
        for (int n = 0; n < 6; n++) {
            int c0 = (wave * 6 + n) * 16;
            bf16x8 bb = *(const bf16x8*)(BA2 + (((kt * 4 + quad) * 384) + c0 + l15) * 8);
            acc3[n] = MFMA(af, bb, acc3[n]);
        }
    }
#pragma unroll
    for (int n = 0; n < 6; n++) {
        int col = (wave * 6 + n) * 16 + l15;
        float bb = ib2[col];
#pragma unroll
        for (int r = 0; r < 4; r++) {
            int row = quad * 4 + r;
            sX2[row * 392 + col] = __float2bfloat16(acc3[n][r] + bb);
        }
    }
    __syncthreads();
    for (int idx = t; idx < MT * 128; idx += 256) {
        int a = idx >> 7, f = idx & 127;
        int ga = a0 + a;
        if (ga >= N_ATOMS) continue;
        float x0 = b2f(sX2[a * 392 + f]);
        float x1 = b2f(sX2[a * 392 + 128 + f]);
        float x2 = b2f(sX2[a * 392 + 256 + f]);
        float sd = sSD[a * 128 + f];
        q[(size_t)ga * 128 + f] += x0 + x2 * sd;
#pragma unroll
        for (int s = 0; s < 3; s++) {
            float w = b2f(sW[(a * 3 + s) * 136 + f]);
            size_t off = (size_t)ga * 384 + s * 128 + f;
            float m = mu[off] + x1 * w;
            mu[off] = m;
            mufp8[off] = f32_fp8(m);
        }
    }
}

// ---------------------------------------------------------------------------
__global__ void writeout(const float* __restrict__ q, const float* __restrict__ mu,
                         void* __restrict__ out, const int* __restrict__ flag) {
    int idx = blockIdx.x * blockDim.x + threadIdx.x;
    const int nq = N_ATOMS * FDIM;
    const int ntot = N_ATOMS * 4 * FDIM;
    if (idx >= ntot) return;
    float v = (idx < nq) ? q[idx] : mu[idx - nq];
    if (flag[0] != 0) ((bf16*)out)[idx] = __float2bfloat16(v);
    else              ((float*)out)[idx] = v;
}

extern "C" void kernel_launch(void* const* d_in, const int* in_sizes, int n_in,
                              void* d_out, int out_size, void* d_ws, size_t ws_size,
                              hipStream_t stream) {
    const int* zn    = (const int*)d_in[14];
    const int* idx_i = (const int*)d_in[15];
    const int* idx_j = (const int*)d_in[16];

    char* base = (char*)d_ws;
    int*   flag     = (int*)base;
    float* fp       = (float*)(base + 256);
    float* q        = (float*)(base + 256 + 5926016);
    float* mu       = (float*)(base + 256 + 5926016 + 7680000);
    bf16*  xbf      = (bf16*)(base + 36646272);
    unsigned char* mufp8 = (unsigned char*)(base + 48166272);  // 5.76 MB
    int*   counts   = (int*)(base + 59686272);
    int*   cursor   = (int*)(base + 59746304);
    int*   startarr = (int*)(base + 59806336);
    int*   sorted_j = (int*)(base + 59866368);
    bf16*  edata    = (bf16*)(base + 61066368);   // ends ~75.5 MB
    bf16*  wbf      = (bf16*)fp;                  // aliases dead r_ij region
    bf16*  fWp      = wbf + 3 * WPACK_L;

    detect_dtype<<<1, 256, 0, stream>>>(d_in[0], flag);

    CvtArgs ca;
    for (int t = 0; t < 14; t++) ca.src[t] = d_in[t];
    convert_all<<<(P_TOTAL + 255) / 256, 256, 0, stream>>>(ca, fp, flag);

    const float* r3  = fp + P_RIJ;
    const float* emb = fp + P_EMB;

    hipMemsetAsync(counts, 0, 2 * 60032, stream);
    hist_kernel<<<(N_EDGES + 255) / 256, 256, 0, stream>>>(idx_i, counts);
    scan_kernel<<<1, 256, 0, stream>>>(counts, startarr);
    scatter_kernel<<<(N_EDGES + 255) / 256, 256, 0, stream>>>(
        r3, idx_i, idx_j, startarr, cursor, sorted_j, edata);

    // r3 now dead -> pack weights over it
    pack_all<<<(3 * (WPACK_L + FWP_L) + 255) / 256, 256, 0, stream>>>(fp, wbf, fWp);

    init_state<<<(N_ATOMS * 4 * FDIM + 255) / 256, 256, 0, stream>>>(zn, emb, q, mu);

    for (int l = 0; l < 3; l++) {
        const bf16* wl = wbf + (size_t)l * WPACK_L;
        inter_mfma<<<NBLK, 256, 0, stream>>>(
            q, wl, fp + P_IB1 + l * 128, fp + P_IB2 + l * 384, xbf);
        if (l == 0)
            gather_l0<<<N_ATOMS, 256, 0, stream>>>(
                startarr, sorted_j, edata, xbf, fWp, q, mu);
        else
            gather_mu<<<N_ATOMS, 256, 0, stream>>>(
                startarr, sorted_j, edata, xbf, mufp8, fWp + (size_t)l * FWP_L, q, mu);
        update_mfma<<<NBLK, 256, 0, stream>>>(
            q, mu, mufp8, wl,
            fp + P_MB + l * 256, fp + P_AB1 + l * 128, fp + P_AB2 + l * 384);
    }

    int ntot = N_ATOMS * 4 * FDIM;
    writeout<<<(ntot + 255) / 256, 256, 0, stream>>>(q, mu, d_out, flag);
}